// Round 15
// baseline (967.258 us; speedup 1.0000x reference)
//
#include <hip/hip_runtime.h>
#include <math.h>

// ---- problem constants ----
constexpr int BSZ = 2;            // batch
constexpr int CH  = 256;          // d_model
constexpr int IH  = 96, IW = 96;  // input H, W
constexpr int HSS = 24, WSS = 24; // aggregated H, W
constexpr int SL  = HSS * WSS;    // 576 tokens
constexpr int NHD = 8, DHD = 32;  // heads, head dim
constexpr int CH2 = 512;          // 2*d_model
constexpr int PIX = IH * IW;      // 9216
constexpr int MFFN = BSZ * PIX;   // 18432
constexpr long FEATN = (long)BSZ * PIX * CH;  // 4,718,592 per feature

typedef __attribute__((ext_vector_type(4))) float f32x4;
typedef _Float16 f16;
typedef __attribute__((ext_vector_type(8))) _Float16 f16x8;
typedef __attribute__((ext_vector_type(4))) _Float16 f16x4;

// Swizzle convention: every f16 tensor consumed as a GEMM operand is STORED
// with element column  k' = k ^ ((row & 7) << 3)  (XOR inside each aligned
// 64-element chunk of the K dim). global_load_lds stages it linearly; the
// fragment read applies the same XOR -> bank-conflict-free ds_read_b128.
// XOR value is a multiple of 8 and < 64 -> aligned 8-elem chunks map to
// aligned 8-elem chunks, so f16x8 vector access stays legal.

__device__ inline void gload16(const void* g, void* l) {
  __builtin_amdgcn_global_load_lds(
      (const __attribute__((address_space(1))) unsigned int*)g,
      (__attribute__((address_space(3))) unsigned int*)l, 16, 0, 0);
}

// counted vmcnt wait (immediate must be a literal)
template <int N> __device__ inline void wait_vm() {
  if constexpr (N == 4)      asm volatile("s_waitcnt vmcnt(4)" ::: "memory");
  else                       asm volatile("s_waitcnt vmcnt(0)" ::: "memory");
}

// ---------------- tiled transposes ----------------
// NCHW f32 (two separate inputs) -> f16 swizzled NHWC master (contiguous)
__global__ __launch_bounds__(256) void k_in_tr(const float* __restrict__ in0,
                                               const float* __restrict__ in1,
                                               f16* __restrict__ outh) {
  __shared__ float t[32][33];
  const int b = blockIdx.z;                 // 0..2*BSZ-1
  const float* in = (b < BSZ) ? in0 : in1;
  const int bb = (b < BSZ) ? b : b - BSZ;
  const int p0 = blockIdx.x * 32, c0 = blockIdx.y * 32;
  const int tx = threadIdx.x & 31, ty = threadIdx.x >> 5;
#pragma unroll
  for (int r = 0; r < 4; ++r)
    t[tx][ty + r * 8] = in[((long)bb * CH + c0 + ty + r * 8) * PIX + p0 + tx];
  __syncthreads();
#pragma unroll
  for (int r = 0; r < 4; ++r) {
    long row = (long)b * PIX + p0 + ty + r * 8;         // row & 7 == ty
    outh[row * CH + ((c0 + tx) ^ (ty << 3))] = (f16)t[ty + r * 8][tx];
  }
}

// f16 swizzled NHWC -> NCHW f32 (into d_out); z spans both features
__global__ __launch_bounds__(256) void k_out_tr(const f16* __restrict__ in,
                                                float* __restrict__ out) {
  __shared__ float t[32][33];
  const int b = blockIdx.z;                 // 0..2*BSZ-1
  const int p0 = blockIdx.x * 32, c0 = blockIdx.y * 32;
  const int tx = threadIdx.x & 31, ty = threadIdx.x >> 5;
#pragma unroll
  for (int r = 0; r < 4; ++r)
    t[ty + r * 8][tx] =
        (float)in[((long)b * PIX + p0 + ty + r * 8) * CH + ((c0 + tx) ^ (ty << 3))];
  __syncthreads();
#pragma unroll
  for (int r = 0; r < 4; ++r)
    out[((long)b * CH + c0 + ty + r * 8) * PIX + p0 + tx] = t[tx][ty + r * 8];
}

// ---------------- weight convert+transpose: W[K][N] f32 -> WT[N][K] f16 (swizzled) ----------------
__global__ __launch_bounds__(256) void k_wt(const float* __restrict__ W,
                                            f16* __restrict__ WT,
                                            int K, int N, long strideW, long strideT) {
  const long z = blockIdx.z;
  W  += z * strideW;
  WT += z * strideT;
  __shared__ float t[32][33];
  const int n0 = blockIdx.x * 32, k0 = blockIdx.y * 32;
  const int tx = threadIdx.x & 31, ty = threadIdx.x >> 5;
#pragma unroll
  for (int r = 0; r < 4; ++r)
    t[ty + r * 8][tx] = W[(long)(k0 + ty + r * 8) * N + n0 + tx];
  __syncthreads();
#pragma unroll
  for (int r = 0; r < 4; ++r) {
    int n = n0 + ty + r * 8;
    WT[(long)n * K + ((k0 + tx) ^ ((n & 7) << 3))] = (f16)t[tx][ty + r * 8];
  }
}

// straight f32 -> f16 convert (swizzled rows): mw -> mwH
__global__ __launch_bounds__(256) void k_cvt(const float* __restrict__ W,
                                             f16* __restrict__ O) {
  const int i = blockIdx.x;             // row (in-ch)
  const long z = blockIdx.y;
  const int k = threadIdx.x;
  O[(z * CH + i) * CH + (k ^ ((i & 7) << 3))] = (f16)W[(z * CH + i) * CH + k];
}

// ---------------- RoPE tables (24x24 grid) ----------------
__global__ __launch_bounds__(256) void k_rope_tables(float* __restrict__ sinT,
                                                     float* __restrict__ cosT) {
  int l = blockIdx.x;      // 0..575
  int d = threadIdx.x;     // 0..255
  int ii = l / WSS + 1;
  int jj = l % WSS + 1;
  int kidx = d >> 2;
  bool is_i = ((d >> 1) & 1) == 0;
  float div = expf((float)kidx * -0.14391156831212787f);  // -ln(10000)/64
  float pos = is_i ? (float)ii : (float)jj;
  float ang = pos * div;
  sinT[(long)l * CH + d] = sinf(ang);
  cosT[(long)l * CH + d] = cosf(ang);
}

// ---------------- aggregation: depthwise conv / maxpool + LayerNorm -> f16 (swizzled) ----------------
__global__ __launch_bounds__(64) void k_agg(const f16* __restrict__ x,
                                            const f16* __restrict__ src,
                                            const float* __restrict__ aggw,
                                            const float* __restrict__ g,
                                            const float* __restrict__ bt,
                                            f16* __restrict__ qln,
                                            f16* __restrict__ sln,
                                            int nb, int same) {
  int bi = blockIdx.x;
  int mode = 0;
  const int nblk = nb * SL / 2;
  if (!same && bi >= nblk) { mode = 1; bi -= nblk; }
  const int doConv = same || (mode == 0);
  const int doPool = same || (mode == 1);
  const int tid = threadIdx.x;
  const int tok = tid >> 5, cg = tid & 31;        // token-in-block, channel-group
  const int lg = bi * 2 + tok;                    // global token
  const int b = lg / SL, l = lg - b * SL;
  const int i = l / WSS, j = l - i * WSS;
  const f16* in = mode ? src : x;                 // NHWC f16 swizzled

  float cv[8] = {};
  float mv[8];
#pragma unroll
  for (int e = 0; e < 8; ++e) mv[e] = -INFINITY;
#pragma unroll
  for (int r = 0; r < 4; ++r)
#pragma unroll
    for (int s = 0; s < 4; ++s) {
      const int px = j * 4 + s;
      f16x8 v = *(const f16x8*)&in[(((size_t)b * IH + i * 4 + r) * IW + px) * CH +
                                   ((cg * 8) ^ ((px & 7) << 3))];
#pragma unroll
      for (int e = 0; e < 8; ++e) {
        float f = (float)v[e];
        cv[e] += f * aggw[(cg * 8 + e) * 16 + r * 4 + s];
        mv[e] = fmaxf(mv[e], f);
      }
    }
  const size_t orow = (size_t)(b * SL + l) * CH + ((cg * 8) ^ ((l & 7) << 3));
  if (doConv) {
    float s1 = 0.f, s2 = 0.f;
#pragma unroll
    for (int e = 0; e < 8; ++e) { s1 += cv[e]; s2 += cv[e] * cv[e]; }
#pragma unroll
    for (int d = 1; d < 32; d <<= 1) { s1 += __shfl_xor(s1, d); s2 += __shfl_xor(s2, d); }
    float mu = s1 * (1.f / CH);
    float var = s2 * (1.f / CH) - mu * mu;
    float rs = rsqrtf(var + 1e-5f);
    f16x8 o;
#pragma unroll
    for (int e = 0; e < 8; ++e)
      o[e] = (f16)((cv[e] - mu) * rs * g[cg * 8 + e] + bt[cg * 8 + e]);
    *(f16x8*)&qln[orow] = o;
  }
  if (doPool) {
    float s1 = 0.f, s2 = 0.f;
#pragma unroll
    for (int e = 0; e < 8; ++e) { s1 += mv[e]; s2 += mv[e] * mv[e]; }
#pragma unroll
    for (int d = 1; d < 32; d <<= 1) { s1 += __shfl_xor(s1, d); s2 += __shfl_xor(s2, d); }
    float mu = s1 * (1.f / CH);
    float var = s2 * (1.f / CH) - mu * mu;
    float rs = rsqrtf(var + 1e-5f);
    f16x8 o;
#pragma unroll
    for (int e = 0; e < 8; ++e)
      o[e] = (f16)((mv[e] - mu) * rs * g[cg * 8 + e] + bt[cg * 8 + e]);
    *(f16x8*)&sln[orow] = o;
  }
}

// ---------------- pipelined f16 MFMA GEMM: C = A @ Bt^T ----------------
// OUT: 0 f32 C0; 5 f16 swizzled; 6 f16 linear; 4 QKV-mode
template <int BM, int BN, int OUT>
__global__ __launch_bounds__(256) void k_mm(const f16* __restrict__ A,
                                            const f16* __restrict__ A2,
                                            const f16* __restrict__ Bt,
                                            void* __restrict__ C0, void* __restrict__ C1,
                                            void* __restrict__ C2,
                                            int M, int K, int lda, int ldb,
                                            int koffA, int koffB, int ldc,
                                            const float* __restrict__ sinT,
                                            const float* __restrict__ cosT,
                                            long zsA, long zsB, long zsC) {
  constexpr int BK = 64;
  constexpr int WM = BM / 2, WN = BN / 2;
  constexpr int FM = WM / 16, FN = WN / 16;
  constexpr int RA = BM * BK / 2048, RB = BN * BK / 2048;
  __shared__ f16 As[2][BM * BK];
  __shared__ f16 Bs[2][BN * BK];
  const int tid = threadIdx.x;
  const int lane = tid & 63, w = tid >> 6;
  const int wr = w >> 1, wc = w & 1;
  const int lq = lane & 15, g = lane >> 4;
  const int sw = (lq & 7) << 3;
  const int bm = blockIdx.x * BM, bn = blockIdx.y * BN;
  const long z = blockIdx.z;
  const f16* Ap = ((OUT == 4 && bn >= CH) ? A2 : A) + z * zsA + koffA;
  const f16* Bp = Bt + z * zsB + koffB;

  auto stA = [&](int buf, int k0) {
#pragma unroll
    for (int i = 0; i < RA; ++i) {
      int e = (i * 256 + tid) * 8;
      gload16(Ap + (size_t)(bm + (e >> 6)) * lda + k0 + (e & 63), &As[buf][e]);
    }
  };
  auto stB = [&](int buf, int k0) {
#pragma unroll
    for (int i = 0; i < RB; ++i) {
      int e = (i * 256 + tid) * 8;
      gload16(Bp + (size_t)(bn + (e >> 6)) * ldb + k0 + (e & 63), &Bs[buf][e]);
    }
  };

  f32x4 acc[FM][FN] = {};
  stA(0, 0); stB(0, 0);
  asm volatile("s_waitcnt vmcnt(0)" ::: "memory");
  __syncthreads();
  int cur = 0;
  for (int k0 = 0; k0 < K; k0 += BK) {
    if (k0 + BK < K) { stA(cur ^ 1, k0 + BK); stB(cur ^ 1, k0 + BK); }
#pragma unroll
    for (int ks = 0; ks < 2; ++ks) {
      const int kx = (ks * 32 + g * 8) ^ sw;
      f16x8 a[FM], b[FN];
#pragma unroll
      for (int m = 0; m < FM; ++m)
        a[m] = *(const f16x8*)&As[cur][(wr * WM + m * 16 + lq) * BK + kx];
#pragma unroll
      for (int n = 0; n < FN; ++n)
        b[n] = *(const f16x8*)&Bs[cur][(wc * WN + n * 16 + lq) * BK + kx];
#pragma unroll
      for (int m = 0; m < FM; ++m)
#pragma unroll
        for (int n = 0; n < FN; ++n)
          acc[m][n] = __builtin_amdgcn_mfma_f32_16x16x32_f16(a[m], b[n], acc[m][n], 0, 0, 0);
    }
    __syncthreads();
    cur ^= 1;
  }
  // D layout: col = lane&15 (B index), row = (lane>>4)*4 + r (A index)
#pragma unroll
  for (int m = 0; m < FM; ++m) {
    const int rowb = bm + wr * WM + m * 16 + g * 4;
#pragma unroll
    for (int n = 0; n < FN; ++n) {
      const int col = bn + wc * WN + n * 16 + lq;
#pragma unroll
      for (int r = 0; r < 4; ++r) {
        const int row = rowb + r;
        float v = acc[m][n][r];
        if (OUT == 0) {
          ((float*)C0 + z * zsC)[(size_t)row * ldc + col] = v;
        } else if (OUT == 5) {
          ((f16*)C0 + z * zsC)[(size_t)row * ldc + (col ^ ((row & 7) << 3))] = (f16)v;
        } else if (OUT == 6) {
          ((f16*)C0 + z * zsC)[(size_t)row * ldc + col] = (f16)v;
        } else {  // OUT == 4
          const int b = row / SL, s = row - b * SL;
          const int which = col >> 8;     // 0=Q,1=K,2=V
          const int ch = col & 255;
          float vp = __shfl_xor(v, 1);    // partner channel (ch^1)
          if (which < 2 && sinT) {
            float sn = sinT[(size_t)s * CH + ch];
            float cs = cosT[(size_t)s * CH + ch];
            v = ((lane & 1) == 0) ? v * cs - vp * sn : v * cs + vp * sn;
          }
          if (which == 0) v *= 0.17677669529663687f;  // 1/sqrt(32) folded into Q
          const int h = ch >> 5, d = ch & 31;
          if (which == 0)
            ((f16*)C0)[(((size_t)b * NHD + h) * SL + s) * DHD + d] = (f16)v;
          else if (which == 1)
            ((f16*)C1)[(((size_t)b * NHD + h) * SL + s) * DHD + d] = (f16)v;
          else
            ((f16*)C2)[(((size_t)b * NHD + h) * DHD + d) * SL + s] = (f16)v;
        }
      }
    }
  }
}

// ---------------- fused flash attention, split-S (2 waves/block, 18 tiles each) ----------------
__global__ __launch_bounds__(128) void k_attn(const f16* __restrict__ qh,
                                              const f16* __restrict__ kh,
                                              const f16* __restrict__ vt,
                                              f16* __restrict__ msgA) {
  const int bh = blockIdx.x;
  const int b = bh >> 3, h = bh & 7;
  const int tid = threadIdx.x;
  const int sid = tid >> 6;                  // wave id 0/1 -> S halves
  const int lane = tid & 63;
  const int lq = lane & 15, g = lane >> 4;
  const int q0 = blockIdx.y * 16;

  const f16x8 qf = *(const f16x8*)&qh[((size_t)bh * SL + q0 + lq) * DHD + g * 8];
  const f16* kbase = kh + (size_t)bh * SL * DHD;
  const f16* vbase = vt + (size_t)bh * DHD * SL;
  const int t0 = sid * 18;                   // this wave's tile range [t0, t0+18)

  f16x8 kf = *(const f16x8*)&kbase[((size_t)(t0 * 16 + lq)) * DHD + g * 8];
  f16x4 va = *(const f16x4*)&vbase[(size_t)lq * SL + t0 * 16 + g * 4];
  f16x4 vb = *(const f16x4*)&vbase[(size_t)(16 + lq) * SL + t0 * 16 + g * 4];

  f32x4 o0 = {}, o1 = {};          // O^T[d][q] partial for this S-half
  float m = -1e30f, l = 0.f;
  for (int tt = 0; tt < 18; ++tt) {
    const int t = t0 + tt;
    const int tn = tt < 17 ? t + 1 : t;
    f16x8 kfn = *(const f16x8*)&kbase[((size_t)(tn * 16 + lq)) * DHD + g * 8];
    f16x4 van = *(const f16x4*)&vbase[(size_t)lq * SL + tn * 16 + g * 4];
    f16x4 vbn = *(const f16x4*)&vbase[(size_t)(16 + lq) * SL + tn * 16 + g * 4];
    f32x4 s = __builtin_amdgcn_mfma_f32_16x16x32_f16(kf, qf, (f32x4){0.f, 0.f, 0.f, 0.f}, 0, 0, 0);
    float tm = fmaxf(fmaxf(s[0], s[1]), fmaxf(s[2], s[3]));
    tm = fmaxf(tm, __shfl_xor(tm, 16));
    tm = fmaxf(tm, __shfl_xor(tm, 32));
    if (__any(tm > m + 5.f)) {            // deferred-max rescale (THR=5)
      float mn = fmaxf(m, tm);
      float f = __expf(m - mn);
      o0 *= f; o1 *= f; l *= f; m = mn;
    }
    float e0 = __expf(s[0] - m), e1 = __expf(s[1] - m);
    float e2 = __expf(s[2] - m), e3 = __expf(s[3] - m);
    l += (e0 + e1) + (e2 + e3);
    f16x4 ef = {(f16)e0, (f16)e1, (f16)e2, (f16)e3};
    o0 = __builtin_amdgcn_mfma_f32_16x16x16f16(va, ef, o0, 0, 0, 0);
    o1 = __builtin_amdgcn_mfma_f32_16x16x16f16(vb, ef, o1, 0, 0, 0);
    kf = kfn; va = van; vb = vbn;
  }
  l += __shfl_xor(l, 16);
  l += __shfl_xor(l, 32);                    // wave-total denominator (ref = m)

  // merge the two S-halves through LDS
  __shared__ float mS[2][16], lS[2][16];
  __shared__ float oS[2][2][16][17];
  if (g == 0) { mS[sid][lq] = m; lS[sid][lq] = l; }
#pragma unroll
  for (int r = 0; r < 4; ++r) {
    oS[sid][0][g * 4 + r][lq] = o0[r];
    oS[sid][1][g * 4 + r][lq] = o1[r];
  }
  __syncthreads();
  float m0 = mS[0][lq], m1 = mS[1][lq];
  float l0 = lS[0][lq], l1 = lS[1][lq];
  float mn = fmaxf(m0, m1);
  float f0 = __expf(m0 - mn), f1 = __expf(m1 - mn);
  float inv = 1.f / (l0 * f0 + l1 * f1);
  // wave sid writes output half mt=sid (d = sid*16 + g*4 + r)
  f16x4 ov;
#pragma unroll
  for (int r = 0; r < 4; ++r)
    ov[r] = (f16)((oS[0][sid][g * 4 + r][lq] * f0 + oS[1][sid][g * 4 + r][lq] * f1) * inv);
  const int swz = (lq & 7) << 3;             // token row & 7 == lq & 7
  f16* mrow = msgA + ((size_t)(b * SL + q0 + lq)) * CH;
  *(f16x4*)&mrow[(h * DHD + sid * 16 + g * 4) ^ swz] = ov;
}

// ---------------- unified FFN GEMM: C = A @ Bt^T, 128x128 tile, 512 threads ----------------
// BOTH operands double-buffered (64 KB LDS, 2 blocks/CU). Counted-vmcnt schedule
// (T4): loads stay in flight across barriers; no vmcnt(0) drain in the main loop.
// ZEPI: +interp(Z) +LeakyReLU. Output f16 swizzled.
template <int K, bool ZEPI>
__global__ __launch_bounds__(512) void k_ffn(const f16* __restrict__ A,
                                             const f16* __restrict__ Bt,
                                             const f16* __restrict__ Z,
                                             f16* __restrict__ C,
                                             int lda, int ldc) {
  constexpr int BM = 128, BN = 128, BK = 64;
  constexpr int WM = 32, WN = 64, FM = 2, FN = 4;
  __shared__ f16 As[2][BM * BK];   // 2 x 16 KB
  __shared__ f16 Bs[2][BN * BK];   // 2 x 16 KB
  const int tid = threadIdx.x;
  const int lane = tid & 63, w = tid >> 6;    // 8 waves
  const int wr = w >> 1, wc = w & 1;          // wr 0..3, wc 0..1
  const int lq = lane & 15, g = lane >> 4;
  const int sw = (lq & 7) << 3;
  const int bm = blockIdx.x * BM, bn = blockIdx.y * BN;

  auto stage = [&](int buf, int k0) {
#pragma unroll
    for (int i = 0; i < 2; ++i) {
      int e = (i * 512 + tid) * 8;
      gload16(A + (size_t)(bm + (e >> 6)) * lda + k0 + (e & 63), &As[buf][e]);
    }
#pragma unroll
    for (int i = 0; i < 2; ++i) {
      int e = (i * 512 + tid) * 8;
      gload16(Bt + (size_t)(bn + (e >> 6)) * 512 + k0 + (e & 63), &Bs[buf][e]);
    }
  };

  f32x4 acc[FM][FN] = {};
  stage(0, 0);
  stage(1, BK);
  int cur = 0;
  for (int k0 = 0; k0 < K; k0 += BK) {
    // wait for buffer `cur` (4 newer loads for the other buffer may stay in flight)
    if (k0 + BK < K) wait_vm<4>(); else wait_vm<0>();
    __builtin_amdgcn_s_barrier();
    __builtin_amdgcn_sched_barrier(0);
#pragma unroll
    for (int ks = 0; ks < 2; ++ks) {
      const int kx = (ks * 32 + g * 8) ^ sw;
      f16x8 a[FM], b[FN];
#pragma unroll
      for (int m = 0; m < FM; ++m)
        a[m] = *(const f16x8*)&As[cur][(wr * WM + m * 16 + lq) * BK + kx];
#pragma unroll
      for (int n = 0; n < FN; ++n)
        b[n] = *(const f16x8*)&Bs[cur][(wc * WN + n * 16 + lq) * BK + kx];
#pragma unroll
      for (int m = 0; m < FM; ++m)
#pragma unroll
        for (int n = 0; n < FN; ++n)
          acc[m][n] = __builtin_amdgcn_mfma_f32_16x16x32_f16(a[m], b[n], acc[m][n], 0, 0, 0);
    }
    __builtin_amdgcn_s_barrier();               // all waves done reading `cur`
    if (k0 + 2 * BK < K) stage(cur, k0 + 2 * BK);
    cur ^= 1;
  }
#pragma unroll
  for (int m = 0; m < FM; ++m) {
    const int rowb = bm + wr * WM + m * 16 + g * 4;
#pragma unroll
    for (int r = 0; r < 4; ++r) {
      const int row = rowb + r;
      const int rs = (row & 7) << 3;
      if (ZEPI) {
        const int b = row / PIX;
        const int p = row - b * PIX;
        const int y = p / IW, xx = p - y * IW;
        float sy = (y + 0.5f) * 0.25f - 0.5f;
        float sx = (xx + 0.5f) * 0.25f - 0.5f;
        int y0 = (int)floorf(sy); float wy = sy - y0;
        int x0 = (int)floorf(sx); float wx = sx - x0;
        int y1 = min(y0 + 1, HSS - 1); y0 = max(y0, 0);
        int x1 = min(x0 + 1, WSS - 1); x0 = max(x0, 0);
        const f16* Zb = Z + (size_t)b * SL * CH2;
        const f16* z00 = Zb + (size_t)(y0 * WSS + x0) * CH2;
        const f16* z01 = Zb + (size_t)(y0 * WSS + x1) * CH2;
        const f16* z10 = Zb + (size_t)(y1 * WSS + x0) * CH2;
        const f16* z11 = Zb + (size_t)(y1 * WSS + x1) * CH2;
        float w00 = (1.f - wy) * (1.f - wx), w01 = (1.f - wy) * wx;
        float w10 = wy * (1.f - wx), w11 = wy * wx;
#pragma unroll
        for (int n = 0; n < FN; ++n) {
          const int col = bn + wc * WN + n * 16 + lq;
          float v = acc[m][n][r] + w00 * (float)z00[col] + w01 * (float)z01[col] +
                    w10 * (float)z10[col] + w11 * (float)z11[col];
          v = v >= 0.f ? v : 0.01f * v;
          C[(size_t)row * ldc + (col ^ rs)] = (f16)v;
        }
      } else {
#pragma unroll
        for (int n = 0; n < FN; ++n) {
          const int col = bn + wc * WN + n * 16 + lq;
          C[(size_t)row * ldc + (col ^ rs)] = (f16)acc[m][n][r];
        }
      }
    }
  }
}

// ---------------- LayerNorm(h2) + residual into xh (both f16 swizzled) ----------------
__global__ __launch_bounds__(256) void k_lnres(const f16* __restrict__ h2,
                                               const float* __restrict__ g2,
                                               const float* __restrict__ b2,
                                               f16* __restrict__ xh) {
  __shared__ float gS[256], bS[256];
  const int tid = threadIdx.x;
  gS[tid] = g2[tid]; bS[tid] = b2[tid];
  __syncthreads();
  const int row = blockIdx.x * 8 + (tid >> 5);
  const int c = tid & 31;
  const int swr = (row & 7) << 3;
  const size_t off = (size_t)row * CH + ((c * 8) ^ swr);
  f16x8 v = *(const f16x8*)&h2[off];
  float s1 = 0.f, s2 = 0.f;
  float f[8];
#pragma unroll
  for (int e = 0; e < 8; ++e) { f[e] = (float)v[e]; s1 += f[e]; s2 += f[e] * f[e]; }
#pragma unroll
  for (int d = 1; d < 32; d <<= 1) { s1 += __shfl_xor(s1, d); s2 += __shfl_xor(s2, d); }
  float mu = s1 * (1.f / CH);
  float var = s2 * (1.f / CH) - mu * mu;
  float rs = rsqrtf(var + 1e-5f);
  f16x8 x = *(const f16x8*)&xh[off];
  f16x8 o;
#pragma unroll
  for (int e = 0; e < 8; ++e)
    o[e] = (f16)((float)x[e] + (f[e] - mu) * rs * gS[c * 8 + e] + bS[c * 8 + e]);
  *(f16x8*)&xh[off] = o;
}

// ---------------- host-side orchestration ----------------
struct LayerP {
  const float *aggw, *g1, *b1, *g2, *b2;
  const f16 *qkvT, *w1T, *w2T, *wcT;
};

struct Bufs {
  f16 *qln, *sln, *msgA, *h1, *h2, *xh;
  f16 *qh, *kh, *vt;
  f16 *Zbuf;
  const float *sinT, *cosT;
};

static void attn_part(long xoff, long soff, const LayerP& p, bool rope, int nb,
                      const Bufs& B, hipStream_t stream) {
  const int M = nb * SL;
  const int same = (xoff == soff) ? 1 : 0;
  const int nblk = (same ? 1 : 2) * nb * SL / 2;
  k_agg<<<dim3(nblk), 64, 0, stream>>>(B.xh + xoff, B.xh + soff, p.aggw,
                                       p.g1, p.b1, B.qln, B.sln, nb, same);
  const float* sT = rope ? B.sinT : nullptr;
  const float* cT = rope ? B.cosT : nullptr;
  k_mm<32, 64, 4><<<dim3(M / 32, 12), 256, 0, stream>>>(
      B.qln, B.sln, p.qkvT, B.qh, B.kh, B.vt, M, CH, CH, CH, 0, 0, 0, sT, cT, 0, 0, 0);
  k_attn<<<dim3(nb * NHD, 36), 128, 0, stream>>>(B.qh, B.kh, B.vt, B.msgA);
  // Z = msgA @ WcombT^T  (Wcomb = mw @ w1_bot; upsample linearity) -> f16 linear
  k_mm<64, 64, 6><<<dim3(M / 64, 8), 256, 0, stream>>>(
      B.msgA, nullptr, p.wcT, B.Zbuf, nullptr, nullptr, M, CH, CH, CH, 0, 0, CH2,
      nullptr, nullptr, 0, 0, 0);
}

static void ffn_part(int fi, int nf, const f16* Zs, const LayerP& p, const Bufs& B,
                     hipStream_t stream) {
  const int M = nf * MFFN;
  k_ffn<256, true><<<dim3(M / 128, CH2 / 128), 512, 0, stream>>>(
      B.xh + (long)fi * FEATN, p.w1T, Zs, B.h1, CH, CH2);
  k_ffn<512, false><<<dim3(M / 128, CH / 128), 512, 0, stream>>>(
      B.h1, p.w2T, nullptr, B.h2, CH2, CH);
  k_lnres<<<dim3(M / 8), 256, 0, stream>>>(B.h2, p.g2, p.b2, B.xh + (long)fi * FEATN);
}

extern "C" void kernel_launch(void* const* d_in, const int* in_sizes, int n_in,
                              void* d_out, int out_size, void* d_ws, size_t ws_size,
                              hipStream_t stream) {
  const float* in_f0 = (const float*)d_in[0];
  const float* in_f1 = (const float*)d_in[1];
  const float* aggw  = (const float*)d_in[2];
  const float* qw    = (const float*)d_in[3];
  const float* kw    = (const float*)d_in[4];
  const float* vw    = (const float*)d_in[5];
  const float* mw    = (const float*)d_in[6];
  const float* w1    = (const float*)d_in[7];
  const float* w2    = (const float*)d_in[8];
  const float* g1    = (const float*)d_in[9];
  const float* b1    = (const float*)d_in[10];
  const float* g2    = (const float*)d_in[11];
  const float* b2    = (const float*)d_in[12];
  (void)in_sizes; (void)n_in; (void)out_size; (void)ws_size;

  // ---- ws layout (~100 MB; ws >= 268 MB) ----
  char* cur = (char*)d_ws;
  auto alloc = [&](size_t bytes) { void* p = cur; cur += (bytes + 255) & ~(size_t)255; return p; };
  f16*   xh   = (f16*)alloc((size_t)2 * FEATN * 2);      // f16 swizzled master (residual)
  f16*   h1   = (f16*)alloc((size_t)2 * MFFN * CH2 * 2);
  f16*   h2   = (f16*)alloc((size_t)2 * MFFN * CH * 2);
  f16*   Zbuf = (f16*)alloc((size_t)4 * SL * CH2 * 2);
  f16*   msgA = (f16*)alloc((size_t)4 * SL * CH * 2);
  f16*   qln  = (f16*)alloc((size_t)4 * SL * CH * 2);
  f16*   sln  = (f16*)alloc((size_t)4 * SL * CH * 2);
  f16* qh = (f16*)alloc((size_t)4 * NHD * SL * DHD * 2);
  f16* kh = (f16*)alloc((size_t)4 * NHD * SL * DHD * 2);
  f16* vt = (f16*)alloc((size_t)4 * NHD * SL * DHD * 2);
  float* sinT = (float*)alloc((size_t)SL * CH * 4);
  float* cosT = (float*)alloc((size_t)SL * CH * 4);
  f16* qkvT = (f16*)alloc((size_t)8 * 3 * CH * CH * 2);  // [768][256]
  f16* mwH  = (f16*)alloc((size_t)8 * CH * CH * 2);      // [256][256]
  f16* w1T  = (f16*)alloc((size_t)8 * CH2 * CH2 * 2);    // [512][512]
  f16* w2T  = (f16*)alloc((size_t)8 * CH * CH2 * 2);     // [256][512]
  f16* wcT  = (f16*)alloc((size_t)8 * CH2 * CH * 2);     // [512][256]

  // init: transposes, tables, weight prep
  k_in_tr<<<dim3(PIX / 32, CH / 32, 2 * BSZ), 256, 0, stream>>>(in_f0, in_f1, xh);
  k_rope_tables<<<dim3(SL), 256, 0, stream>>>(sinT, cosT);
  k_wt<<<dim3(CH / 32, CH / 32, 8), 256, 0, stream>>>(qw, qkvT, CH, CH, (long)CH * CH, (long)3 * CH * CH);
  k_wt<<<dim3(CH / 32, CH / 32, 8), 256, 0, stream>>>(kw, qkvT + (size_t)CH * CH, CH, CH, (long)CH * CH, (long)3 * CH * CH);
  k_wt<<<dim3(CH / 32, CH / 32, 8), 256, 0, stream>>>(vw, qkvT + (size_t)2 * CH * CH, CH, CH, (long)CH * CH, (long)3 * CH * CH);
  k_cvt<<<dim3(CH, 8), 256, 0, stream>>>(mw, mwH);
  k_wt<<<dim3(CH2 / 32, CH2 / 32, 8), 256, 0, stream>>>(w1, w1T, CH2, CH2, (long)CH2 * CH2, (long)CH2 * CH2);
  k_wt<<<dim3(CH / 32, CH2 / 32, 8), 256, 0, stream>>>(w2, w2T, CH2, CH, (long)CH2 * CH, (long)CH * CH2);
  // WcombT[j][i] = sum_k w1T[j][256+k] * mwH[i][k]   (batched over 8 layers)
  k_mm<64, 64, 5><<<dim3(CH2 / 64, CH / 64, 8), 256, 0, stream>>>(
      w1T, nullptr, mwH, wcT, nullptr, nullptr, CH2, CH, CH2, CH, 256, 0, CH,
      nullptr, nullptr, (long)CH2 * CH2, (long)CH * CH, (long)CH2 * CH);

  Bufs B{qln, sln, msgA, h1, h2, xh, qh, kh, vt, Zbuf, sinT, cosT};

  for (int i = 0; i < 8; ++i) {
    LayerP p{aggw + (long)i * CH * 16,
             g1 + i * CH, b1 + i * CH, g2 + i * CH, b2 + i * CH,
             qkvT + (long)i * 3 * CH * CH,
             w1T + (long)i * CH2 * CH2, w2T + (long)i * CH * CH2,
             wcT + (long)i * CH2 * CH};
    if ((i & 1) == 0) {
      // self: f0,f1 independent -> batch attention nb=4 and FFN over both features
      attn_part(0, 0, p, true, 4, B, stream);
      ffn_part(0, 2, Zbuf, p, B, stream);
    } else {
      // cross: sequential (feat1's source is the UPDATED feat0)
      attn_part(0, FEATN, p, false, 2, B, stream);
      ffn_part(0, 1, Zbuf, p, B, stream);
      attn_part(FEATN, 0, p, false, 2, B, stream);
      ffn_part(1, 1, Zbuf, p, B, stream);
    }
  }

  // final: f16 swizzled NHWC -> NCHW f32 directly into d_out (z spans both features)
  k_out_tr<<<dim3(PIX / 32, CH / 32, 2 * BSZ), 256, 0, stream>>>(xh, (float*)d_out);
}

// Round 16
// 950.474 us; speedup vs baseline: 1.0177x; 1.0177x over previous
//
#include <hip/hip_runtime.h>
#include <math.h>

// ---- problem constants ----
constexpr int BSZ = 2;            // batch
constexpr int CH  = 256;          // d_model
constexpr int IH  = 96, IW = 96;  // input H, W
constexpr int HSS = 24, WSS = 24; // aggregated H, W
constexpr int SL  = HSS * WSS;    // 576 tokens
constexpr int NHD = 8, DHD = 32;  // heads, head dim
constexpr int CH2 = 512;          // 2*d_model
constexpr int PIX = IH * IW;      // 9216
constexpr int MFFN = BSZ * PIX;   // 18432
constexpr long FEATN = (long)BSZ * PIX * CH;  // 4,718,592 per feature

typedef __attribute__((ext_vector_type(4))) float f32x4;
typedef _Float16 f16;
typedef __attribute__((ext_vector_type(8))) _Float16 f16x8;
typedef __attribute__((ext_vector_type(4))) _Float16 f16x4;

// Swizzle convention: every f16 tensor consumed as a GEMM operand is STORED
// with element column  k' = k ^ ((row & 7) << 3)  (XOR inside each aligned
// 64-element chunk of the K dim). global_load_lds stages it linearly; the
// fragment read applies the same XOR -> bank-conflict-free ds_read_b128.
// XOR value is a multiple of 8 and < 64 -> aligned 8-elem chunks map to
// aligned 8-elem chunks, so f16x8 vector access stays legal.

__device__ inline void gload16(const void* g, void* l) {
  __builtin_amdgcn_global_load_lds(
      (const __attribute__((address_space(1))) unsigned int*)g,
      (__attribute__((address_space(3))) unsigned int*)l, 16, 0, 0);
}

// ---------------- tiled transposes ----------------
// NCHW f32 (two separate inputs) -> f16 swizzled NHWC master (contiguous)
__global__ __launch_bounds__(256) void k_in_tr(const float* __restrict__ in0,
                                               const float* __restrict__ in1,
                                               f16* __restrict__ outh) {
  __shared__ float t[32][33];
  const int b = blockIdx.z;                 // 0..2*BSZ-1
  const float* in = (b < BSZ) ? in0 : in1;
  const int bb = (b < BSZ) ? b : b - BSZ;
  const int p0 = blockIdx.x * 32, c0 = blockIdx.y * 32;
  const int tx = threadIdx.x & 31, ty = threadIdx.x >> 5;
#pragma unroll
  for (int r = 0; r < 4; ++r)
    t[tx][ty + r * 8] = in[((long)bb * CH + c0 + ty + r * 8) * PIX + p0 + tx];
  __syncthreads();
#pragma unroll
  for (int r = 0; r < 4; ++r) {
    long row = (long)b * PIX + p0 + ty + r * 8;         // row & 7 == ty
    outh[row * CH + ((c0 + tx) ^ (ty << 3))] = (f16)t[ty + r * 8][tx];
  }
}

// f16 swizzled NHWC -> NCHW f32 (into d_out); z spans both features
__global__ __launch_bounds__(256) void k_out_tr(const f16* __restrict__ in,
                                                float* __restrict__ out) {
  __shared__ float t[32][33];
  const int b = blockIdx.z;                 // 0..2*BSZ-1
  const int p0 = blockIdx.x * 32, c0 = blockIdx.y * 32;
  const int tx = threadIdx.x & 31, ty = threadIdx.x >> 5;
#pragma unroll
  for (int r = 0; r < 4; ++r)
    t[ty + r * 8][tx] =
        (float)in[((long)b * PIX + p0 + ty + r * 8) * CH + ((c0 + tx) ^ (ty << 3))];
  __syncthreads();
#pragma unroll
  for (int r = 0; r < 4; ++r)
    out[((long)b * CH + c0 + ty + r * 8) * PIX + p0 + tx] = t[tx][ty + r * 8];
}

// ---------------- weight convert+transpose: W[K][N] f32 -> WT[N][K] f16 (swizzled) ----------------
__global__ __launch_bounds__(256) void k_wt(const float* __restrict__ W,
                                            f16* __restrict__ WT,
                                            int K, int N, long strideW, long strideT) {
  const long z = blockIdx.z;
  W  += z * strideW;
  WT += z * strideT;
  __shared__ float t[32][33];
  const int n0 = blockIdx.x * 32, k0 = blockIdx.y * 32;
  const int tx = threadIdx.x & 31, ty = threadIdx.x >> 5;
#pragma unroll
  for (int r = 0; r < 4; ++r)
    t[ty + r * 8][tx] = W[(long)(k0 + ty + r * 8) * N + n0 + tx];
  __syncthreads();
#pragma unroll
  for (int r = 0; r < 4; ++r) {
    int n = n0 + ty + r * 8;
    WT[(long)n * K + ((k0 + tx) ^ ((n & 7) << 3))] = (f16)t[tx][ty + r * 8];
  }
}

// merged q/k/v weight transpose: z = layer*3 + widx; dest [768][256] per layer
__global__ __launch_bounds__(256) void k_wt3(const float* __restrict__ qw,
                                             const float* __restrict__ kw,
                                             const float* __restrict__ vw,
                                             f16* __restrict__ qkvT) {
  const int z = blockIdx.z;
  const int layer = z / 3, widx = z - layer * 3;
  const float* W = (widx == 0 ? qw : (widx == 1 ? kw : vw)) + (long)layer * CH * CH;
  f16* WT = qkvT + ((long)layer * 3 + widx) * CH * CH;
  __shared__ float t[32][33];
  const int n0 = blockIdx.x * 32, k0 = blockIdx.y * 32;
  const int tx = threadIdx.x & 31, ty = threadIdx.x >> 5;
#pragma unroll
  for (int r = 0; r < 4; ++r)
    t[ty + r * 8][tx] = W[(long)(k0 + ty + r * 8) * CH + n0 + tx];
  __syncthreads();
#pragma unroll
  for (int r = 0; r < 4; ++r) {
    int n = n0 + ty + r * 8;
    WT[(long)n * CH + ((k0 + tx) ^ ((n & 7) << 3))] = (f16)t[tx][ty + r * 8];
  }
}

// straight f32 -> f16 convert (swizzled rows): mw -> mwH
__global__ __launch_bounds__(256) void k_cvt(const float* __restrict__ W,
                                             f16* __restrict__ O) {
  const int i = blockIdx.x;             // row (in-ch)
  const long z = blockIdx.y;
  const int k = threadIdx.x;
  O[(z * CH + i) * CH + (k ^ ((i & 7) << 3))] = (f16)W[(z * CH + i) * CH + k];
}

// ---------------- RoPE tables (24x24 grid) ----------------
__global__ __launch_bounds__(256) void k_rope_tables(float* __restrict__ sinT,
                                                     float* __restrict__ cosT) {
  int l = blockIdx.x;      // 0..575
  int d = threadIdx.x;     // 0..255
  int ii = l / WSS + 1;
  int jj = l % WSS + 1;
  int kidx = d >> 2;
  bool is_i = ((d >> 1) & 1) == 0;
  float div = expf((float)kidx * -0.14391156831212787f);  // -ln(10000)/64
  float pos = is_i ? (float)ii : (float)jj;
  float ang = pos * div;
  sinT[(long)l * CH + d] = sinf(ang);
  cosT[(long)l * CH + d] = cosf(ang);
}

// ---------------- aggregation: depthwise conv / maxpool + LayerNorm -> f16 (swizzled) ----------------
__global__ __launch_bounds__(64) void k_agg(const f16* __restrict__ x,
                                            const f16* __restrict__ src,
                                            const float* __restrict__ aggw,
                                            const float* __restrict__ g,
                                            const float* __restrict__ bt,
                                            f16* __restrict__ qln,
                                            f16* __restrict__ sln,
                                            int nb, int same) {
  int bi = blockIdx.x;
  int mode = 0;
  const int nblk = nb * SL / 2;
  if (!same && bi >= nblk) { mode = 1; bi -= nblk; }
  const int doConv = same || (mode == 0);
  const int doPool = same || (mode == 1);
  const int tid = threadIdx.x;
  const int tok = tid >> 5, cg = tid & 31;        // token-in-block, channel-group
  const int lg = bi * 2 + tok;                    // global token
  const int b = lg / SL, l = lg - b * SL;
  const int i = l / WSS, j = l - i * WSS;
  const f16* in = mode ? src : x;                 // NHWC f16 swizzled

  float cv[8] = {};
  float mv[8];
#pragma unroll
  for (int e = 0; e < 8; ++e) mv[e] = -INFINITY;
#pragma unroll
  for (int r = 0; r < 4; ++r)
#pragma unroll
    for (int s = 0; s < 4; ++s) {
      const int px = j * 4 + s;
      f16x8 v = *(const f16x8*)&in[(((size_t)b * IH + i * 4 + r) * IW + px) * CH +
                                   ((cg * 8) ^ ((px & 7) << 3))];
#pragma unroll
      for (int e = 0; e < 8; ++e) {
        float f = (float)v[e];
        cv[e] += f * aggw[(cg * 8 + e) * 16 + r * 4 + s];
        mv[e] = fmaxf(mv[e], f);
      }
    }
  const size_t orow = (size_t)(b * SL + l) * CH + ((cg * 8) ^ ((l & 7) << 3));
  if (doConv) {
    float s1 = 0.f, s2 = 0.f;
#pragma unroll
    for (int e = 0; e < 8; ++e) { s1 += cv[e]; s2 += cv[e] * cv[e]; }
#pragma unroll
    for (int d = 1; d < 32; d <<= 1) { s1 += __shfl_xor(s1, d); s2 += __shfl_xor(s2, d); }
    float mu = s1 * (1.f / CH);
    float var = s2 * (1.f / CH) - mu * mu;
    float rs = rsqrtf(var + 1e-5f);
    f16x8 o;
#pragma unroll
    for (int e = 0; e < 8; ++e)
      o[e] = (f16)((cv[e] - mu) * rs * g[cg * 8 + e] + bt[cg * 8 + e]);
    *(f16x8*)&qln[orow] = o;
  }
  if (doPool) {
    float s1 = 0.f, s2 = 0.f;
#pragma unroll
    for (int e = 0; e < 8; ++e) { s1 += mv[e]; s2 += mv[e] * mv[e]; }
#pragma unroll
    for (int d = 1; d < 32; d <<= 1) { s1 += __shfl_xor(s1, d); s2 += __shfl_xor(s2, d); }
    float mu = s1 * (1.f / CH);
    float var = s2 * (1.f / CH) - mu * mu;
    float rs = rsqrtf(var + 1e-5f);
    f16x8 o;
#pragma unroll
    for (int e = 0; e < 8; ++e)
      o[e] = (f16)((mv[e] - mu) * rs * g[cg * 8 + e] + bt[cg * 8 + e]);
    *(f16x8*)&sln[orow] = o;
  }
}

// ---------------- pipelined f16 MFMA GEMM: C = A @ Bt^T ----------------
// OUT: 0 f32 C0; 5 f16 swizzled; 6 f16 linear; 4 QKV-mode
template <int BM, int BN, int OUT>
__global__ __launch_bounds__(256) void k_mm(const f16* __restrict__ A,
                                            const f16* __restrict__ A2,
                                            const f16* __restrict__ Bt,
                                            void* __restrict__ C0, void* __restrict__ C1,
                                            void* __restrict__ C2,
                                            int M, int K, int lda, int ldb,
                                            int koffA, int koffB, int ldc,
                                            const float* __restrict__ sinT,
                                            const float* __restrict__ cosT,
                                            long zsA, long zsB, long zsC) {
  constexpr int BK = 64;
  constexpr int WM = BM / 2, WN = BN / 2;
  constexpr int FM = WM / 16, FN = WN / 16;
  constexpr int RA = BM * BK / 2048, RB = BN * BK / 2048;
  __shared__ f16 As[2][BM * BK];
  __shared__ f16 Bs[2][BN * BK];
  const int tid = threadIdx.x;
  const int lane = tid & 63, w = tid >> 6;
  const int wr = w >> 1, wc = w & 1;
  const int lq = lane & 15, g = lane >> 4;
  const int sw = (lq & 7) << 3;
  const int bm = blockIdx.x * BM, bn = blockIdx.y * BN;
  const long z = blockIdx.z;
  const f16* Ap = ((OUT == 4 && bn >= CH) ? A2 : A) + z * zsA + koffA;
  const f16* Bp = Bt + z * zsB + koffB;

  auto stA = [&](int buf, int k0) {
#pragma unroll
    for (int i = 0; i < RA; ++i) {
      int e = (i * 256 + tid) * 8;
      gload16(Ap + (size_t)(bm + (e >> 6)) * lda + k0 + (e & 63), &As[buf][e]);
    }
  };
  auto stB = [&](int buf, int k0) {
#pragma unroll
    for (int i = 0; i < RB; ++i) {
      int e = (i * 256 + tid) * 8;
      gload16(Bp + (size_t)(bn + (e >> 6)) * ldb + k0 + (e & 63), &Bs[buf][e]);
    }
  };

  f32x4 acc[FM][FN] = {};
  stA(0, 0); stB(0, 0);
  asm volatile("s_waitcnt vmcnt(0)" ::: "memory");
  __syncthreads();
  int cur = 0;
  for (int k0 = 0; k0 < K; k0 += BK) {
    if (k0 + BK < K) { stA(cur ^ 1, k0 + BK); stB(cur ^ 1, k0 + BK); }
#pragma unroll
    for (int ks = 0; ks < 2; ++ks) {
      const int kx = (ks * 32 + g * 8) ^ sw;
      f16x8 a[FM], b[FN];
#pragma unroll
      for (int m = 0; m < FM; ++m)
        a[m] = *(const f16x8*)&As[cur][(wr * WM + m * 16 + lq) * BK + kx];
#pragma unroll
      for (int n = 0; n < FN; ++n)
        b[n] = *(const f16x8*)&Bs[cur][(wc * WN + n * 16 + lq) * BK + kx];
#pragma unroll
      for (int m = 0; m < FM; ++m)
#pragma unroll
        for (int n = 0; n < FN; ++n)
          acc[m][n] = __builtin_amdgcn_mfma_f32_16x16x32_f16(a[m], b[n], acc[m][n], 0, 0, 0);
    }
    __syncthreads();
    cur ^= 1;
  }
  // D layout: col = lane&15 (B index), row = (lane>>4)*4 + r (A index)
#pragma unroll
  for (int m = 0; m < FM; ++m) {
    const int rowb = bm + wr * WM + m * 16 + g * 4;
#pragma unroll
    for (int n = 0; n < FN; ++n) {
      const int col = bn + wc * WN + n * 16 + lq;
#pragma unroll
      for (int r = 0; r < 4; ++r) {
        const int row = rowb + r;
        float v = acc[m][n][r];
        if (OUT == 0) {
          ((float*)C0 + z * zsC)[(size_t)row * ldc + col] = v;
        } else if (OUT == 5) {
          ((f16*)C0 + z * zsC)[(size_t)row * ldc + (col ^ ((row & 7) << 3))] = (f16)v;
        } else if (OUT == 6) {
          ((f16*)C0 + z * zsC)[(size_t)row * ldc + col] = (f16)v;
        } else {  // OUT == 4
          const int b = row / SL, s = row - b * SL;
          const int which = col >> 8;     // 0=Q,1=K,2=V
          const int ch = col & 255;
          float vp = __shfl_xor(v, 1);    // partner channel (ch^1)
          if (which < 2 && sinT) {
            float sn = sinT[(size_t)s * CH + ch];
            float cs = cosT[(size_t)s * CH + ch];
            v = ((lane & 1) == 0) ? v * cs - vp * sn : v * cs + vp * sn;
          }
          if (which == 0) v *= 0.17677669529663687f;  // 1/sqrt(32) folded into Q
          const int h = ch >> 5, d = ch & 31;
          if (which == 0)
            ((f16*)C0)[(((size_t)b * NHD + h) * SL + s) * DHD + d] = (f16)v;
          else if (which == 1)
            ((f16*)C1)[(((size_t)b * NHD + h) * SL + s) * DHD + d] = (f16)v;
          else
            ((f16*)C2)[(((size_t)b * NHD + h) * DHD + d) * SL + s] = (f16)v;
        }
      }
    }
  }
}

// ---------------- fused flash attention, split-S (2 waves/block, 18 tiles each) ----------------
__global__ __launch_bounds__(128) void k_attn(const f16* __restrict__ qh,
                                              const f16* __restrict__ kh,
                                              const f16* __restrict__ vt,
                                              f16* __restrict__ msgA) {
  const int bh = blockIdx.x;
  const int b = bh >> 3, h = bh & 7;
  const int tid = threadIdx.x;
  const int sid = tid >> 6;                  // wave id 0/1 -> S halves
  const int lane = tid & 63;
  const int lq = lane & 15, g = lane >> 4;
  const int q0 = blockIdx.y * 16;

  const f16x8 qf = *(const f16x8*)&qh[((size_t)bh * SL + q0 + lq) * DHD + g * 8];
  const f16* kbase = kh + (size_t)bh * SL * DHD;
  const f16* vbase = vt + (size_t)bh * DHD * SL;
  const int t0 = sid * 18;                   // this wave's tile range [t0, t0+18)

  f16x8 kf = *(const f16x8*)&kbase[((size_t)(t0 * 16 + lq)) * DHD + g * 8];
  f16x4 va = *(const f16x4*)&vbase[(size_t)lq * SL + t0 * 16 + g * 4];
  f16x4 vb = *(const f16x4*)&vbase[(size_t)(16 + lq) * SL + t0 * 16 + g * 4];

  f32x4 o0 = {}, o1 = {};          // O^T[d][q] partial for this S-half
  float m = -1e30f, l = 0.f;
  for (int tt = 0; tt < 18; ++tt) {
    const int t = t0 + tt;
    const int tn = tt < 17 ? t + 1 : t;
    f16x8 kfn = *(const f16x8*)&kbase[((size_t)(tn * 16 + lq)) * DHD + g * 8];
    f16x4 van = *(const f16x4*)&vbase[(size_t)lq * SL + tn * 16 + g * 4];
    f16x4 vbn = *(const f16x4*)&vbase[(size_t)(16 + lq) * SL + tn * 16 + g * 4];
    f32x4 s = __builtin_amdgcn_mfma_f32_16x16x32_f16(kf, qf, (f32x4){0.f, 0.f, 0.f, 0.f}, 0, 0, 0);
    float tm = fmaxf(fmaxf(s[0], s[1]), fmaxf(s[2], s[3]));
    tm = fmaxf(tm, __shfl_xor(tm, 16));
    tm = fmaxf(tm, __shfl_xor(tm, 32));
    if (__any(tm > m + 5.f)) {            // deferred-max rescale (THR=5)
      float mn = fmaxf(m, tm);
      float f = __expf(m - mn);
      o0 *= f; o1 *= f; l *= f; m = mn;
    }
    float e0 = __expf(s[0] - m), e1 = __expf(s[1] - m);
    float e2 = __expf(s[2] - m), e3 = __expf(s[3] - m);
    l += (e0 + e1) + (e2 + e3);
    f16x4 ef = {(f16)e0, (f16)e1, (f16)e2, (f16)e3};
    o0 = __builtin_amdgcn_mfma_f32_16x16x16f16(va, ef, o0, 0, 0, 0);
    o1 = __builtin_amdgcn_mfma_f32_16x16x16f16(vb, ef, o1, 0, 0, 0);
    kf = kfn; va = van; vb = vbn;
  }
  l += __shfl_xor(l, 16);
  l += __shfl_xor(l, 32);                    // wave-total denominator (ref = m)

  // merge the two S-halves through LDS
  __shared__ float mS[2][16], lS[2][16];
  __shared__ float oS[2][2][16][17];
  if (g == 0) { mS[sid][lq] = m; lS[sid][lq] = l; }
#pragma unroll
  for (int r = 0; r < 4; ++r) {
    oS[sid][0][g * 4 + r][lq] = o0[r];
    oS[sid][1][g * 4 + r][lq] = o1[r];
  }
  __syncthreads();
  float m0 = mS[0][lq], m1 = mS[1][lq];
  float l0 = lS[0][lq], l1 = lS[1][lq];
  float mn = fmaxf(m0, m1);
  float f0 = __expf(m0 - mn), f1 = __expf(m1 - mn);
  float inv = 1.f / (l0 * f0 + l1 * f1);
  // wave sid writes output half mt=sid (d = sid*16 + g*4 + r)
  f16x4 ov;
#pragma unroll
  for (int r = 0; r < 4; ++r)
    ov[r] = (f16)((oS[0][sid][g * 4 + r][lq] * f0 + oS[1][sid][g * 4 + r][lq] * f1) * inv);
  const int swz = (lq & 7) << 3;             // token row & 7 == lq & 7
  f16* mrow = msgA + ((size_t)(b * SL + q0 + lq)) * CH;
  *(f16x4*)&mrow[(h * DHD + sid * 16 + g * 4) ^ swz] = ov;
}

// ---------------- unified FFN GEMM: C = A @ Bt^T, 128x128 tile, 512 threads ----------------
// BOTH operands double-buffered (64 KB LDS, 2 blocks/CU); single barrier per K-step
// (round-14 proven schedule: prefetch next under current MFMA, drain at end barrier).
// ZEPI: +interp(Z) +LeakyReLU. Output f16 swizzled.
template <int K, bool ZEPI>
__global__ __launch_bounds__(512) void k_ffn(const f16* __restrict__ A,
                                             const f16* __restrict__ Bt,
                                             const f16* __restrict__ Z,
                                             f16* __restrict__ C,
                                             int lda, int ldc) {
  constexpr int BM = 128, BN = 128, BK = 64;
  constexpr int WM = 32, WN = 64, FM = 2, FN = 4;
  __shared__ f16 As[2][BM * BK];   // 2 x 16 KB
  __shared__ f16 Bs[2][BN * BK];   // 2 x 16 KB
  const int tid = threadIdx.x;
  const int lane = tid & 63, w = tid >> 6;    // 8 waves
  const int wr = w >> 1, wc = w & 1;          // wr 0..3, wc 0..1
  const int lq = lane & 15, g = lane >> 4;
  const int sw = (lq & 7) << 3;
  const int bm = blockIdx.x * BM, bn = blockIdx.y * BN;

  auto stA = [&](int buf, int k0) {
#pragma unroll
    for (int i = 0; i < 2; ++i) {
      int e = (i * 512 + tid) * 8;
      gload16(A + (size_t)(bm + (e >> 6)) * lda + k0 + (e & 63), &As[buf][e]);
    }
  };
  auto stB = [&](int buf, int k0) {
#pragma unroll
    for (int i = 0; i < 2; ++i) {
      int e = (i * 512 + tid) * 8;
      gload16(Bt + (size_t)(bn + (e >> 6)) * 512 + k0 + (e & 63), &Bs[buf][e]);
    }
  };

  f32x4 acc[FM][FN] = {};
  stA(0, 0); stB(0, 0);
  asm volatile("s_waitcnt vmcnt(0)" ::: "memory");
  __syncthreads();
  int cur = 0;
  for (int k0 = 0; k0 < K; k0 += BK) {
    if (k0 + BK < K) { stA(cur ^ 1, k0 + BK); stB(cur ^ 1, k0 + BK); }
#pragma unroll
    for (int ks = 0; ks < 2; ++ks) {
      const int kx = (ks * 32 + g * 8) ^ sw;
      f16x8 a[FM], b[FN];
#pragma unroll
      for (int m = 0; m < FM; ++m)
        a[m] = *(const f16x8*)&As[cur][(wr * WM + m * 16 + lq) * BK + kx];
#pragma unroll
      for (int n = 0; n < FN; ++n)
        b[n] = *(const f16x8*)&Bs[cur][(wc * WN + n * 16 + lq) * BK + kx];
#pragma unroll
      for (int m = 0; m < FM; ++m)
#pragma unroll
        for (int n = 0; n < FN; ++n)
          acc[m][n] = __builtin_amdgcn_mfma_f32_16x16x32_f16(a[m], b[n], acc[m][n], 0, 0, 0);
    }
    __syncthreads();    // drains the prefetch once per step
    cur ^= 1;
  }
#pragma unroll
  for (int m = 0; m < FM; ++m) {
    const int rowb = bm + wr * WM + m * 16 + g * 4;
#pragma unroll
    for (int r = 0; r < 4; ++r) {
      const int row = rowb + r;
      const int rs = (row & 7) << 3;
      if (ZEPI) {
        const int b = row / PIX;
        const int p = row - b * PIX;
        const int y = p / IW, xx = p - y * IW;
        float sy = (y + 0.5f) * 0.25f - 0.5f;
        float sx = (xx + 0.5f) * 0.25f - 0.5f;
        int y0 = (int)floorf(sy); float wy = sy - y0;
        int x0 = (int)floorf(sx); float wx = sx - x0;
        int y1 = min(y0 + 1, HSS - 1); y0 = max(y0, 0);
        int x1 = min(x0 + 1, WSS - 1); x0 = max(x0, 0);
        const f16* Zb = Z + (size_t)b * SL * CH2;
        const f16* z00 = Zb + (size_t)(y0 * WSS + x0) * CH2;
        const f16* z01 = Zb + (size_t)(y0 * WSS + x1) * CH2;
        const f16* z10 = Zb + (size_t)(y1 * WSS + x0) * CH2;
        const f16* z11 = Zb + (size_t)(y1 * WSS + x1) * CH2;
        float w00 = (1.f - wy) * (1.f - wx), w01 = (1.f - wy) * wx;
        float w10 = wy * (1.f - wx), w11 = wy * wx;
#pragma unroll
        for (int n = 0; n < FN; ++n) {
          const int col = bn + wc * WN + n * 16 + lq;
          float v = acc[m][n][r] + w00 * (float)z00[col] + w01 * (float)z01[col] +
                    w10 * (float)z10[col] + w11 * (float)z11[col];
          v = v >= 0.f ? v : 0.01f * v;
          C[(size_t)row * ldc + (col ^ rs)] = (f16)v;
        }
      } else {
#pragma unroll
        for (int n = 0; n < FN; ++n) {
          const int col = bn + wc * WN + n * 16 + lq;
          C[(size_t)row * ldc + (col ^ rs)] = (f16)acc[m][n][r];
        }
      }
    }
  }
}

// ---------------- LayerNorm(h2) + residual into xh (both f16 swizzled) ----------------
__global__ __launch_bounds__(256) void k_lnres(const f16* __restrict__ h2,
                                               const float* __restrict__ g2,
                                               const float* __restrict__ b2,
                                               f16* __restrict__ xh) {
  __shared__ float gS[256], bS[256];
  const int tid = threadIdx.x;
  gS[tid] = g2[tid]; bS[tid] = b2[tid];
  __syncthreads();
  const int row = blockIdx.x * 8 + (tid >> 5);
  const int c = tid & 31;
  const int swr = (row & 7) << 3;
  const size_t off = (size_t)row * CH + ((c * 8) ^ swr);
  f16x8 v = *(const f16x8*)&h2[off];
  float s1 = 0.f, s2 = 0.f;
  float f[8];
#pragma unroll
  for (int e = 0; e < 8; ++e) { f[e] = (float)v[e]; s1 += f[e]; s2 += f[e] * f[e]; }
#pragma unroll
  for (int d = 1; d < 32; d <<= 1) { s1 += __shfl_xor(s1, d); s2 += __shfl_xor(s2, d); }
  float mu = s1 * (1.f / CH);
  float var = s2 * (1.f / CH) - mu * mu;
  float rs = rsqrtf(var + 1e-5f);
  f16x8 x = *(const f16x8*)&xh[off];
  f16x8 o;
#pragma unroll
  for (int e = 0; e < 8; ++e)
    o[e] = (f16)((float)x[e] + (f[e] - mu) * rs * gS[c * 8 + e] + bS[c * 8 + e]);
  *(f16x8*)&xh[off] = o;
}

// ---------------- host-side orchestration ----------------
struct LayerP {
  const float *aggw, *g1, *b1, *g2, *b2;
  const f16 *qkvT, *w1T, *w2T, *wcT;
};

struct Bufs {
  f16 *qln, *sln, *msgA, *h1, *h2, *xh;
  f16 *qh, *kh, *vt;
  f16 *Zbuf;
  const float *sinT, *cosT;
};

static void attn_part(long xoff, long soff, const LayerP& p, bool rope, int nb,
                      const Bufs& B, hipStream_t stream) {
  const int M = nb * SL;
  const int same = (xoff == soff) ? 1 : 0;
  const int nblk = (same ? 1 : 2) * nb * SL / 2;
  k_agg<<<dim3(nblk), 64, 0, stream>>>(B.xh + xoff, B.xh + soff, p.aggw,
                                       p.g1, p.b1, B.qln, B.sln, nb, same);
  const float* sT = rope ? B.sinT : nullptr;
  const float* cT = rope ? B.cosT : nullptr;
  k_mm<32, 64, 4><<<dim3(M / 32, 12), 256, 0, stream>>>(
      B.qln, B.sln, p.qkvT, B.qh, B.kh, B.vt, M, CH, CH, CH, 0, 0, 0, sT, cT, 0, 0, 0);
  k_attn<<<dim3(nb * NHD, 36), 128, 0, stream>>>(B.qh, B.kh, B.vt, B.msgA);
  // Z = msgA @ WcombT^T  (Wcomb = mw @ w1_bot; upsample linearity) -> f16 linear
  k_mm<64, 64, 6><<<dim3(M / 64, 8), 256, 0, stream>>>(
      B.msgA, nullptr, p.wcT, B.Zbuf, nullptr, nullptr, M, CH, CH, CH, 0, 0, CH2,
      nullptr, nullptr, 0, 0, 0);
}

static void ffn_part(int fi, int nf, const f16* Zs, const LayerP& p, const Bufs& B,
                     hipStream_t stream) {
  const int M = nf * MFFN;
  k_ffn<256, true><<<dim3(M / 128, CH2 / 128), 512, 0, stream>>>(
      B.xh + (long)fi * FEATN, p.w1T, Zs, B.h1, CH, CH2);
  k_ffn<512, false><<<dim3(M / 128, CH / 128), 512, 0, stream>>>(
      B.h1, p.w2T, nullptr, B.h2, CH2, CH);
  k_lnres<<<dim3(M / 8), 256, 0, stream>>>(B.h2, p.g2, p.b2, B.xh + (long)fi * FEATN);
}

extern "C" void kernel_launch(void* const* d_in, const int* in_sizes, int n_in,
                              void* d_out, int out_size, void* d_ws, size_t ws_size,
                              hipStream_t stream) {
  const float* in_f0 = (const float*)d_in[0];
  const float* in_f1 = (const float*)d_in[1];
  const float* aggw  = (const float*)d_in[2];
  const float* qw    = (const float*)d_in[3];
  const float* kw    = (const float*)d_in[4];
  const float* vw    = (const float*)d_in[5];
  const float* mw    = (const float*)d_in[6];
  const float* w1    = (const float*)d_in[7];
  const float* w2    = (const float*)d_in[8];
  const float* g1    = (const float*)d_in[9];
  const float* b1    = (const float*)d_in[10];
  const float* g2    = (const float*)d_in[11];
  const float* b2    = (const float*)d_in[12];
  (void)in_sizes; (void)n_in; (void)out_size; (void)ws_size;

  // ---- ws layout (~100 MB; ws >= 268 MB) ----
  char* cur = (char*)d_ws;
  auto alloc = [&](size_t bytes) { void* p = cur; cur += (bytes + 255) & ~(size_t)255; return p; };
  f16*   xh   = (f16*)alloc((size_t)2 * FEATN * 2);      // f16 swizzled master (residual)
  f16*   h1   = (f16*)alloc((size_t)2 * MFFN * CH2 * 2);
  f16*   h2   = (f16*)alloc((size_t)2 * MFFN * CH * 2);
  f16*   Zbuf = (f16*)alloc((size_t)4 * SL * CH2 * 2);
  f16*   msgA = (f16*)alloc((size_t)4 * SL * CH * 2);
  f16*   qln  = (f16*)alloc((size_t)4 * SL * CH * 2);
  f16*   sln  = (f16*)alloc((size_t)4 * SL * CH * 2);
  f16* qh = (f16*)alloc((size_t)4 * NHD * SL * DHD * 2);
  f16* kh = (f16*)alloc((size_t)4 * NHD * SL * DHD * 2);
  f16* vt = (f16*)alloc((size_t)4 * NHD * SL * DHD * 2);
  float* sinT = (float*)alloc((size_t)SL * CH * 4);
  float* cosT = (float*)alloc((size_t)SL * CH * 4);
  f16* qkvT = (f16*)alloc((size_t)8 * 3 * CH * CH * 2);  // [768][256]
  f16* mwH  = (f16*)alloc((size_t)8 * CH * CH * 2);      // [256][256]
  f16* w1T  = (f16*)alloc((size_t)8 * CH2 * CH2 * 2);    // [512][512]
  f16* w2T  = (f16*)alloc((size_t)8 * CH * CH2 * 2);     // [256][512]
  f16* wcT  = (f16*)alloc((size_t)8 * CH2 * CH * 2);     // [512][256]

  // init: transposes, tables, weight prep (q/k/v merged into one launch)
  k_in_tr<<<dim3(PIX / 32, CH / 32, 2 * BSZ), 256, 0, stream>>>(in_f0, in_f1, xh);
  k_rope_tables<<<dim3(SL), 256, 0, stream>>>(sinT, cosT);
  k_wt3<<<dim3(CH / 32, CH / 32, 24), 256, 0, stream>>>(qw, kw, vw, qkvT);
  k_cvt<<<dim3(CH, 8), 256, 0, stream>>>(mw, mwH);
  k_wt<<<dim3(CH2 / 32, CH2 / 32, 8), 256, 0, stream>>>(w1, w1T, CH2, CH2, (long)CH2 * CH2, (long)CH2 * CH2);
  k_wt<<<dim3(CH / 32, CH2 / 32, 8), 256, 0, stream>>>(w2, w2T, CH2, CH, (long)CH2 * CH, (long)CH * CH2);
  // WcombT[j][i] = sum_k w1T[j][256+k] * mwH[i][k]   (batched over 8 layers)
  k_mm<64, 64, 5><<<dim3(CH2 / 64, CH / 64, 8), 256, 0, stream>>>(
      w1T, nullptr, mwH, wcT, nullptr, nullptr, CH2, CH, CH2, CH, 256, 0, CH,
      nullptr, nullptr, (long)CH2 * CH2, (long)CH * CH, (long)CH2 * CH);

  Bufs B{qln, sln, msgA, h1, h2, xh, qh, kh, vt, Zbuf, sinT, cosT};

  for (int i = 0; i < 8; ++i) {
    LayerP p{aggw + (long)i * CH * 16,
             g1 + i * CH, b1 + i * CH, g2 + i * CH, b2 + i * CH,
             qkvT + (long)i * 3 * CH * CH,
             w1T + (long)i * CH2 * CH2, w2T + (long)i * CH * CH2,
             wcT + (long)i * CH2 * CH};
    if ((i & 1) == 0) {
      // self: f0,f1 independent -> batch attention nb=4 and FFN over both features
      attn_part(0, 0, p, true, 4, B, stream);
      ffn_part(0, 2, Zbuf, p, B, stream);
    } else {
      // cross: sequential (feat1's source is the UPDATED feat0)
      attn_part(0, FEATN, p, false, 2, B, stream);
      ffn_part(0, 1, Zbuf, p, B, stream);
      attn_part(FEATN, 0, p, false, 2, B, stream);
      ffn_part(1, 1, Zbuf, p, B, stream);
    }
  }

  // final: f16 swizzled NHWC -> NCHW f32 directly into d_out (z spans both features)
  k_out_tr<<<dim3(PIX / 32, CH / 32, 2 * BSZ), 256, 0, stream>>>(xh, (float*)d_out);
}